// Round 6
// baseline (165.947 us; speedup 1.0000x reference)
//
#include <hip/hip_runtime.h>

// Problem constants (from reference)
#define N_NODES 12500
#define N_EDGES 200000
#define DIM 32          // IN == OUT == ATTN == 32
#define N_REL 200
#define N_BASES 50

#define OUT_ELEMS   (N_NODES * DIM)
#define ZERO_BLOCKS ((OUT_ELEMS + 1023) / 1024)   // 391

// counting-sort params: 256 thr x 4 edges = 1024 edges/block
#define EDGES_PER_HBLOCK 1024
#define HIST_BLOCKS ((N_EDGES + EDGES_PER_HBLOCK - 1) / EDGES_PER_HBLOCK)  // 196

// ws layout (bytes):
//   [0, 409600)         bf16 relw_bf[200][32][32]
//   [409600, +8192)     bf16 aw_bf[32][128]
//   [417792, +2048)     bf16 slwT_bf[32][32]   (transposed [j][i])
//   [419840, +800)      int  bins[200]
//   [420864, +800)      int  cursors[200]
//   [421888, +800000)   int  perm[200000]
#define AWBF_OFF  409600
#define SLWT_OFF  417792
#define BINS_OFF  419840
#define CURS_OFF  420864
#define PERM_OFF  421888
#define WS_NEEDED (PERM_OFF + N_EDGES * 4)

typedef __attribute__((ext_vector_type(8))) short short8;   // 8 bf16 (4 VGPRs)
typedef __attribute__((ext_vector_type(4))) float f32x4;    // MFMA acc
typedef __attribute__((ext_vector_type(4))) unsigned short us4;

__device__ __forceinline__ unsigned short f2bf(float x) {
    union { float f; unsigned u; } v; v.f = x;
    unsigned r = (v.u + 0x7FFFu + ((v.u >> 16) & 1u)) >> 16;
    return (unsigned short)r;
}

__device__ __forceinline__ short8 cvt8(float4 a, float4 b) {
    short8 r;
    r[0] = (short)f2bf(a.x); r[1] = (short)f2bf(a.y);
    r[2] = (short)f2bf(a.z); r[3] = (short)f2bf(a.w);
    r[4] = (short)f2bf(b.x); r[5] = (short)f2bf(b.y);
    r[6] = (short)f2bf(b.z); r[7] = (short)f2bf(b.w);
    return r;
}

__device__ __forceinline__ int clampi(int x, int hi) {
    return x < 0 ? 0 : (x >= hi ? hi - 1 : x);
}

#define MFMA(A, B, C) __builtin_amdgcn_mfma_f32_16x16x32_bf16(A, B, C, 0, 0, 0)

// K1 prep: [0,200) rel_w bf16; [200,591) zero out; block 591 cvt Aw/slwT + zero bins.
__global__ __launch_bounds__(256) void prep_kernel(
    const float* __restrict__ weight,   // [50,32,32]
    const float* __restrict__ w_comp,   // [200,50]
    const float* __restrict__ Aw,       // [32,128]
    const float* __restrict__ slw,      // [32,32]
    unsigned short* __restrict__ relw_bf,
    unsigned short* __restrict__ aw_bf,
    unsigned short* __restrict__ slwT_bf,
    int* __restrict__ bins,
    float* __restrict__ out)
{
    int b = blockIdx.x, tid = threadIdx.x;
    if (b < N_REL) {
        __shared__ float wc[N_BASES];
        if (tid < N_BASES) wc[tid] = w_comp[b * N_BASES + tid];
        __syncthreads();
        const float* wp = weight + tid * 4;
        float4 acc = make_float4(0.f, 0.f, 0.f, 0.f);
        #pragma unroll 10
        for (int bb = 0; bb < N_BASES; bb++) {
            float4 w = *(const float4*)(wp + bb * 1024);
            float c = wc[bb];
            acc.x = fmaf(c, w.x, acc.x); acc.y = fmaf(c, w.y, acc.y);
            acc.z = fmaf(c, w.z, acc.z); acc.w = fmaf(c, w.w, acc.w);
        }
        us4 o;
        o[0] = f2bf(acc.x); o[1] = f2bf(acc.y);
        o[2] = f2bf(acc.z); o[3] = f2bf(acc.w);
        *(us4*)(relw_bf + b * 1024 + tid * 4) = o;
    } else if (b < N_REL + ZERO_BLOCKS) {
        int base = (b - N_REL) * 1024 + tid * 4;
        if (base + 3 < OUT_ELEMS)
            *(float4*)(out + base) = make_float4(0.f, 0.f, 0.f, 0.f);
        else
            for (int k = 0; k < 4; k++)
                if (base + k < OUT_ELEMS) out[base + k] = 0.f;
    } else {
        for (int x = tid; x < 32 * 128; x += 256) aw_bf[x] = f2bf(Aw[x]);
        for (int x = tid; x < 32 * 32; x += 256) {
            int i = x >> 5, j = x & 31;
            slwT_bf[j * 32 + i] = f2bf(slw[x]);
        }
        if (tid < N_REL) bins[tid] = 0;
    }
}

// K2: relation histogram (LDS-local then one global atomic per bin per block)
__global__ __launch_bounds__(256) void hist_kernel(
    const int* __restrict__ rel, int* __restrict__ bins)
{
    __shared__ int lb[N_REL];
    int tid = threadIdx.x;
    if (tid < N_REL) lb[tid] = 0;
    __syncthreads();
    int base = blockIdx.x * EDGES_PER_HBLOCK + tid;
    #pragma unroll
    for (int k = 0; k < 4; k++) {
        int e = base + k * 256;
        if (e < N_EDGES) atomicAdd(&lb[clampi(rel[e], N_REL)], 1);
    }
    __syncthreads();
    if (tid < N_REL && lb[tid] > 0) atomicAdd(&bins[tid], lb[tid]);
}

// K3: exclusive scan of 200 bins -> cursors (single block, serial: 200 elems)
__global__ __launch_bounds__(64) void scan_kernel(
    const int* __restrict__ bins, int* __restrict__ cursors)
{
    if (threadIdx.x == 0) {
        int run = 0;
        for (int r = 0; r < N_REL; r++) { cursors[r] = run; run += bins[r]; }
    }
}

// K4: scatter edge ids into relation-sorted perm
__global__ __launch_bounds__(256) void scatter_kernel(
    const int* __restrict__ rel, int* __restrict__ cursors,
    int* __restrict__ perm)
{
    __shared__ int lb[N_REL];     // local counts -> then global base
    int tid = threadIdx.x;
    if (tid < N_REL) lb[tid] = 0;
    __syncthreads();
    int base = blockIdx.x * EDGES_PER_HBLOCK + tid;
    int myr[4], myrank[4];
    #pragma unroll
    for (int k = 0; k < 4; k++) {
        int e = base + k * 256;
        myr[k] = -1;
        if (e < N_EDGES) {
            myr[k] = clampi(rel[e], N_REL);
            myrank[k] = atomicAdd(&lb[myr[k]], 1);
        }
    }
    __syncthreads();
    if (tid < N_REL) {
        int c = lb[tid];
        lb[tid] = c > 0 ? atomicAdd(&cursors[tid], c) : 0;
    }
    __syncthreads();
    #pragma unroll
    for (int k = 0; k < 4; k++)
        if (myr[k] >= 0) perm[lb[myr[k]] + myrank[k]] = base + k * 256;
}

// K5 edge kernel: one wave = 16 relation-sorted edges. h & cur via MFMA
// (weights in register fragments); msg via VALU — after sorting, each msg
// load inst is one L1-resident 64B line broadcast instead of 16 scattered
// L2 segments. LDS only for per-wave msg relayout into C/D layout.
__global__ __launch_bounds__(256) void edge_kernel(
    const float* __restrict__ node_feat,  // [N,32]
    const float* __restrict__ ttr,        // [E,32]
    const float* __restrict__ tre,        // [E,32]
    const float* __restrict__ Ab,         // [32]
    const float* __restrict__ Bw,         // [1,32]
    const float* __restrict__ Bb,         // [1]
    const int*  __restrict__ edge0,       // [E]
    const int*  __restrict__ edge1,       // [E]
    const int*  __restrict__ rel,         // [E]
    const int*  __restrict__ perm,        // [E] sorted order (or null)
    const unsigned short* __restrict__ relw_bf, // [200][32][32] bf16
    const unsigned short* __restrict__ aw_bf,   // [32][128] bf16
    const unsigned short* __restrict__ slwT_bf, // [32][32]  bf16 (T)
    float* __restrict__ out)              // [N,32] fp32 (pre-zeroed)
{
    __shared__ float msgL[4 * 16 * 36];   // per-wave 16x36 slice (9.2 KB)

    int tid  = threadIdx.x;
    int wave = tid >> 6;
    int lane = tid & 63;
    int m = lane & 15;          // edge row (A-frag) / out col n (B,C/D frag)
    int q = lane >> 4;          // quad: k-range / row-group
    int base = blockIdx.x * 64 + wave * 16;   // 3125*64 == 200000 exactly

    int s_ld = 0, t_ld = 0, r_ld = 0, e_ld = 0;
    if (lane < 16) {
        int eid = perm ? perm[base + lane] : (base + lane);
        eid = clampi(eid, N_EDGES);
        e_ld = eid;
        s_ld = clampi(edge0[eid], N_NODES);
        t_ld = clampi(edge1[eid], N_NODES);
        r_ld = clampi(rel[eid],   N_REL);
    }
    int s_m   = __shfl(s_ld, m, 64);
    int t_m   = __shfl(t_ld, m, 64);
    int eid_m = __shfl(e_ld, m, 64);

    // ---- gather A-operand data (lane holds edge m, k = 8q..8q+7) ----
    const float* sp = node_feat + s_m * DIM + q * 8;
    float4 sv0 = *(const float4*)sp, sv1 = *(const float4*)(sp + 4);
    const float* tp = node_feat + t_m * DIM + q * 8;
    float4 tv0 = *(const float4*)tp, tv1 = *(const float4*)(tp + 4);
    const float* rp = tre + eid_m * DIM + q * 8;
    float4 rv0 = *(const float4*)rp, rv1 = *(const float4*)(rp + 4);
    const float* qp = ttr + eid_m * DIM + q * 8;
    float4 qv0 = *(const float4*)qp, qv1 = *(const float4*)(qp + 4);

    short8 fsrc = cvt8(sv0, sv1);
    short8 ftgt = cvt8(tv0, tv1);
    short8 fre  = cvt8(rv0, rv1);
    short8 ftr  = cvt8(qv0, qv1);

    // ---- B-operand fragments (lane: n = m, k = 8q..8q+7) ----
    short8 bA[4][2], bS[2];
    #pragma unroll
    for (int hh = 0; hh < 2; hh++) {
        #pragma unroll
        for (int c = 0; c < 4; c++)
            bA[c][hh] = *(const short8*)(aw_bf + (16 * hh + m) * 128 + 32 * c + 8 * q);
        bS[hh] = *(const short8*)(slwT_bf + (16 * hh + m) * 32 + 8 * q);
    }

    // ---- MFMAs: h = Ecat @ Aw^T + Ab ; cur = tgt @ slw ----
    float ab0 = Ab[m], ab1 = Ab[16 + m];
    f32x4 hacc0 = {ab0, ab0, ab0, ab0};
    f32x4 hacc1 = {ab1, ab1, ab1, ab1};
    f32x4 cacc0 = {0.f, 0.f, 0.f, 0.f};
    f32x4 cacc1 = {0.f, 0.f, 0.f, 0.f};

    hacc0 = MFMA(fsrc, bA[0][0], hacc0);  hacc1 = MFMA(fsrc, bA[0][1], hacc1);
    hacc0 = MFMA(ftgt, bA[1][0], hacc0);  hacc1 = MFMA(ftgt, bA[1][1], hacc1);
    hacc0 = MFMA(fre,  bA[2][0], hacc0);  hacc1 = MFMA(fre,  bA[2][1], hacc1);
    hacc0 = MFMA(ftr,  bA[3][0], hacc0);  hacc1 = MFMA(ftr,  bA[3][1], hacc1);
    cacc0 = MFMA(ftgt, bS[0], cacc0);     cacc1 = MFMA(ftgt, bS[1], cacc1);

    // ---- msg (fp32 acc, bf16 weights): lane = (edge e_loc, col-chunk cq) ----
    int e_loc = lane >> 2;
    int cq    = lane & 3;
    int r_e = __shfl(r_ld, e_loc, 64);
    const unsigned short* rwb = relw_bf + r_e * 1024 + cq * 8;
    float sf[8] = {sv0.x, sv0.y, sv0.z, sv0.w, sv1.x, sv1.y, sv1.z, sv1.w};
    float msg[8] = {0.f, 0.f, 0.f, 0.f, 0.f, 0.f, 0.f, 0.f};
    #pragma unroll
    for (int k = 0; k < 32; k++) {
        float s_k = __shfl(sf[k & 7], e_loc + 16 * (k >> 3), 64);
        union { short8 s; unsigned u[4]; } W;
        W.s = *(const short8*)(rwb + k * 32);
        #pragma unroll
        for (int p = 0; p < 4; p++) {
            float lo = __uint_as_float(W.u[p] << 16);
            float hi = __uint_as_float(W.u[p] & 0xffff0000u);
            msg[2 * p]     = fmaf(s_k, lo, msg[2 * p]);
            msg[2 * p + 1] = fmaf(s_k, hi, msg[2 * p + 1]);
        }
    }

    // relayout msg -> C/D layout via per-wave LDS slice (no barrier needed)
    float* ml = msgL + wave * (16 * 36);
    *(float4*)(ml + e_loc * 36 + cq * 8)     = make_float4(msg[0], msg[1], msg[2], msg[3]);
    *(float4*)(ml + e_loc * 36 + cq * 8 + 4) = make_float4(msg[4], msg[5], msg[6], msg[7]);

    // ---- epilogue: gate a = sigmoid(relu(h)@Bw + Bb), combine, scatter ----
    float bw0 = Bw[m], bw1 = Bw[16 + m], Bb0 = Bb[0];
    float av[4];
    #pragma unroll
    for (int v = 0; v < 4; v++) {
        float p = fmaxf(hacc0[v], 0.f) * bw0 + fmaxf(hacc1[v], 0.f) * bw1;
        p += __shfl_xor(p, 1, 16);
        p += __shfl_xor(p, 2, 16);
        p += __shfl_xor(p, 4, 16);
        p += __shfl_xor(p, 8, 16);
        av[v] = 1.f / (1.f + __expf(-(p + Bb0)));
    }
    #pragma unroll
    for (int v = 0; v < 4; v++) {
        int row = 4 * q + v;
        int tv = __shfl(t_ld, row, 64);
        float m0 = ml[row * 36 + m];
        float m1 = ml[row * 36 + 16 + m];
        atomicAdd(&out[tv * DIM + m],      cacc0[v] + m0 * av[v]);
        atomicAdd(&out[tv * DIM + 16 + m], cacc1[v] + m1 * av[v]);
    }
}

extern "C" void kernel_launch(void* const* d_in, const int* in_sizes, int n_in,
                              void* d_out, int out_size, void* d_ws, size_t ws_size,
                              hipStream_t stream) {
    const float* node_feat = (const float*)d_in[0];
    const float* ttr       = (const float*)d_in[1];
    const float* tre       = (const float*)d_in[2];
    const float* weight    = (const float*)d_in[3];
    const float* w_comp    = (const float*)d_in[4];
    const float* slw       = (const float*)d_in[5];
    const float* Aw        = (const float*)d_in[6];
    const float* Ab        = (const float*)d_in[7];
    const float* Bw        = (const float*)d_in[8];
    const float* Bb        = (const float*)d_in[9];
    const int*  total_edge = (const int*)d_in[10];
    const int*  rel        = (const int*)d_in[11];
    const int*  edge0 = total_edge;
    const int*  edge1 = total_edge + N_EDGES;

    unsigned short* relw_bf = (unsigned short*)d_ws;
    unsigned short* aw_bf   = (unsigned short*)((char*)d_ws + AWBF_OFF);
    unsigned short* slwT_bf = (unsigned short*)((char*)d_ws + SLWT_OFF);
    int* bins    = (int*)((char*)d_ws + BINS_OFF);
    int* cursors = (int*)((char*)d_ws + CURS_OFF);
    int* perm    = (int*)((char*)d_ws + PERM_OFF);
    float* out = (float*)d_out;

    bool use_sort = ws_size >= (size_t)WS_NEEDED;

    prep_kernel<<<N_REL + ZERO_BLOCKS + 1, 256, 0, stream>>>(
        weight, w_comp, Aw, slw, relw_bf, aw_bf, slwT_bf, bins, out);

    if (use_sort) {
        hist_kernel<<<HIST_BLOCKS, 256, 0, stream>>>(rel, bins);
        scan_kernel<<<1, 64, 0, stream>>>(bins, cursors);
        scatter_kernel<<<HIST_BLOCKS, 256, 0, stream>>>(rel, cursors, perm);
    }

    edge_kernel<<<N_EDGES / 64, 256, 0, stream>>>(
        node_feat, ttr, tre, Ab, Bw, Bb,
        edge0, edge1, rel, use_sort ? perm : (const int*)nullptr,
        relw_bf, aw_bf, slwT_bf, out);
}

// Round 7
// 159.464 us; speedup vs baseline: 1.0407x; 1.0407x over previous
//
#include <hip/hip_runtime.h>

// Problem constants (from reference)
#define N_NODES 12500
#define N_EDGES 200000
#define DIM 32          // IN == OUT == ATTN == 32
#define N_REL 200
#define N_BASES 50

#define OUT_ELEMS   (N_NODES * DIM)
#define ZERO_BLOCKS ((OUT_ELEMS + 1023) / 1024)   // 391

#define EDGES_PER_HBLOCK 1024
#define HIST_BLOCKS ((N_EDGES + EDGES_PER_HBLOCK - 1) / EDGES_PER_HBLOCK)  // 196

// ws layout (bytes):
//   [0, 409600)       bf16 relw_bf[200][32][32]  (TRANSPOSED [o][i] when sorted,
//                                                 row-major [i][o] when unsorted)
//   [409600, +8192)   bf16 aw_bf[32][128]
//   [417792, +2048)   bf16 slwT_bf[32][32]   (transposed [j][i])
//   [419840, +800)    int  bins[200]
//   [420640, +800)    int  gcur[200]
//   [421440, ...)     perm: int4[200000] (tier A) or int[200000] (tier B)
#define AWBF_OFF  409600
#define SLWT_OFF  417792
#define BINS_OFF  419840
#define GCUR_OFF  420640
#define PERM_OFF  421440
#define WS_A (PERM_OFF + N_EDGES * 16)   // 3,621,440
#define WS_B (PERM_OFF + N_EDGES * 4)    // 1,221,440 (proven available in R6)

typedef __attribute__((ext_vector_type(8))) short short8;   // 8 bf16 (4 VGPRs)
typedef __attribute__((ext_vector_type(4))) float f32x4;    // MFMA acc
typedef __attribute__((ext_vector_type(4))) unsigned short us4;

__device__ __forceinline__ unsigned short f2bf(float x) {
    union { float f; unsigned u; } v; v.f = x;
    unsigned r = (v.u + 0x7FFFu + ((v.u >> 16) & 1u)) >> 16;
    return (unsigned short)r;
}
__device__ __forceinline__ float bf2f(unsigned short u) {
    return __uint_as_float(((unsigned)u) << 16);
}

__device__ __forceinline__ short8 cvt8(float4 a, float4 b) {
    short8 r;
    r[0] = (short)f2bf(a.x); r[1] = (short)f2bf(a.y);
    r[2] = (short)f2bf(a.z); r[3] = (short)f2bf(a.w);
    r[4] = (short)f2bf(b.x); r[5] = (short)f2bf(b.y);
    r[6] = (short)f2bf(b.z); r[7] = (short)f2bf(b.w);
    return r;
}

__device__ __forceinline__ int clampi(int x, int hi) {
    return x < 0 ? 0 : (x >= hi ? hi - 1 : x);
}

#define MFMA(A, B, C) __builtin_amdgcn_mfma_f32_16x16x32_bf16(A, B, C, 0, 0, 0)

// K1 prep (fused): [0,200) rel_w; [200,591) zero out; 591 cvt Aw/slwT;
// [592, 592+196) relation histogram (bins pre-zeroed by memsetAsync).
__global__ __launch_bounds__(256) void prep_kernel(
    const float* __restrict__ weight,   // [50,32,32]
    const float* __restrict__ w_comp,   // [200,50]
    const float* __restrict__ Aw,       // [32,128]
    const float* __restrict__ slw,      // [32,32]
    const int*  __restrict__ rel,       // [E]
    unsigned short* __restrict__ relw_bf,
    unsigned short* __restrict__ aw_bf,
    unsigned short* __restrict__ slwT_bf,
    int* __restrict__ bins,
    float* __restrict__ out,
    int sorted)
{
    int b = blockIdx.x, tid = threadIdx.x;
    if (b < N_REL) {
        __shared__ float wc[N_BASES];
        if (tid < N_BASES) wc[tid] = w_comp[b * N_BASES + tid];
        __syncthreads();
        const float* wp = weight + tid * 4;
        float4 acc = make_float4(0.f, 0.f, 0.f, 0.f);
        #pragma unroll 10
        for (int bb = 0; bb < N_BASES; bb++) {
            float4 w = *(const float4*)(wp + bb * 1024);
            float c = wc[bb];
            acc.x = fmaf(c, w.x, acc.x); acc.y = fmaf(c, w.y, acc.y);
            acc.z = fmaf(c, w.z, acc.z); acc.w = fmaf(c, w.w, acc.w);
        }
        int i = (tid * 4) >> 5, o = (tid * 4) & 31;   // rel_w[i][o..o+3]
        if (sorted) {
            // transposed (B-frag) layout: relw[o+j][i]
            relw_bf[b * 1024 + (o + 0) * 32 + i] = f2bf(acc.x);
            relw_bf[b * 1024 + (o + 1) * 32 + i] = f2bf(acc.y);
            relw_bf[b * 1024 + (o + 2) * 32 + i] = f2bf(acc.z);
            relw_bf[b * 1024 + (o + 3) * 32 + i] = f2bf(acc.w);
        } else {
            us4 ov;
            ov[0] = f2bf(acc.x); ov[1] = f2bf(acc.y);
            ov[2] = f2bf(acc.z); ov[3] = f2bf(acc.w);
            *(us4*)(relw_bf + b * 1024 + tid * 4) = ov;
        }
    } else if (b < N_REL + ZERO_BLOCKS) {
        int base = (b - N_REL) * 1024 + tid * 4;
        if (base + 3 < OUT_ELEMS)
            *(float4*)(out + base) = make_float4(0.f, 0.f, 0.f, 0.f);
        else
            for (int k = 0; k < 4; k++)
                if (base + k < OUT_ELEMS) out[base + k] = 0.f;
    } else if (b == N_REL + ZERO_BLOCKS) {
        for (int x = tid; x < 32 * 128; x += 256) aw_bf[x] = f2bf(Aw[x]);
        for (int x = tid; x < 32 * 32; x += 256) {
            int i = x >> 5, j = x & 31;
            slwT_bf[j * 32 + i] = f2bf(slw[x]);
        }
    } else {
        // histogram block
        __shared__ int lb[N_REL];
        if (tid < N_REL) lb[tid] = 0;
        __syncthreads();
        int base = (b - (N_REL + ZERO_BLOCKS + 1)) * EDGES_PER_HBLOCK + tid;
        #pragma unroll
        for (int k = 0; k < 4; k++) {
            int e = base + k * 256;
            if (e < N_EDGES) atomicAdd(&lb[clampi(rel[e], N_REL)], 1);
        }
        __syncthreads();
        if (tid < N_REL && lb[tid] > 0) atomicAdd(&bins[tid], lb[tid]);
    }
}

// K2 scatter: local prefix-from-bins (no scan kernel) + global rank via gcur.
// Tier A writes int4{s,t,r,eid}; tier B writes int eid.
__global__ __launch_bounds__(256) void scatter_kernel(
    const int* __restrict__ rel,
    const int* __restrict__ edge0,
    const int* __restrict__ edge1,
    const int* __restrict__ bins,
    int* __restrict__ gcur,
    int4* __restrict__ perm4,    // tier A (or null)
    int* __restrict__ permi)     // tier B (or null)
{
    __shared__ int sb[N_REL];    // bins copy
    __shared__ int pref[N_REL];  // exclusive prefix
    __shared__ int lb[N_REL];    // local count -> global base
    int tid = threadIdx.x;
    if (tid < N_REL) { sb[tid] = bins[tid]; lb[tid] = 0; }
    __syncthreads();
    if (tid == 0) {
        int run = 0;
        for (int r = 0; r < N_REL; r++) { pref[r] = run; run += sb[r]; }
    }
    __syncthreads();
    int base = blockIdx.x * EDGES_PER_HBLOCK + tid;
    int myr[4], myrank[4];
    #pragma unroll
    for (int k = 0; k < 4; k++) {
        int e = base + k * 256;
        myr[k] = -1;
        if (e < N_EDGES) {
            myr[k] = clampi(rel[e], N_REL);
            myrank[k] = atomicAdd(&lb[myr[k]], 1);
        }
    }
    __syncthreads();
    if (tid < N_REL) {
        int c = lb[tid];
        lb[tid] = c > 0 ? (pref[tid] + atomicAdd(&gcur[tid], c)) : 0;
    }
    __syncthreads();
    #pragma unroll
    for (int k = 0; k < 4; k++) {
        if (myr[k] >= 0) {
            int e = base + k * 256;
            int pos = lb[myr[k]] + myrank[k];
            if (perm4) {
                int s = clampi(edge0[e], N_NODES);
                int t = clampi(edge1[e], N_NODES);
                perm4[pos] = make_int4(s, t, myr[k], e);
            } else {
                permi[pos] = e;
            }
        }
    }
}

// K3 edge kernel: one wave = 16 relation-sorted edges. h & cur via MFMA;
// msg via MFMA too when the wave's 16 edges share one relation (all but
// ~199 boundary waves) — D lands directly in C/D layout, no LDS relayout.
// Rare mixed waves take a scalar VALU fallback.
__global__ __launch_bounds__(256) void edge_kernel(
    const float* __restrict__ node_feat,  // [N,32]
    const float* __restrict__ ttr,        // [E,32]
    const float* __restrict__ tre,        // [E,32]
    const float* __restrict__ Ab,         // [32]
    const float* __restrict__ Bw,         // [1,32]
    const float* __restrict__ Bb,         // [1]
    const int*  __restrict__ edge0,       // [E]
    const int*  __restrict__ edge1,       // [E]
    const int*  __restrict__ rel,         // [E]
    const int4* __restrict__ perm4,       // tier A packed (or null)
    const int*  __restrict__ permi,       // tier B (or null)
    const unsigned short* __restrict__ relw_bf, // [200][32][32] bf16 (T if sorted)
    const unsigned short* __restrict__ aw_bf,   // [32][128] bf16
    const unsigned short* __restrict__ slwT_bf, // [32][32]  bf16 (T)
    float* __restrict__ out)              // [N,32] fp32 (pre-zeroed)
{
    __shared__ float msgL[4 * 16 * 36];   // fallback relayout slices (9.2 KB)

    int tid  = threadIdx.x;
    int wave = tid >> 6;
    int lane = tid & 63;
    int m = lane & 15;          // edge row (A-frag) / out col n (B,C/D frag)
    int q = lane >> 4;          // quad: k-range / row-group
    int base = blockIdx.x * 64 + wave * 16;   // 3125*64 == 200000 exactly

    int s_ld = 0, t_ld = 0, r_ld = 0, e_ld = 0;
    if (lane < 16) {
        if (perm4) {
            int4 pv = perm4[base + lane];
            s_ld = pv.x; t_ld = pv.y; r_ld = pv.z; e_ld = pv.w;
        } else {
            int eid = permi ? clampi(permi[base + lane], N_EDGES) : (base + lane);
            e_ld = eid;
            s_ld = clampi(edge0[eid], N_NODES);
            t_ld = clampi(edge1[eid], N_NODES);
            r_ld = clampi(rel[eid],   N_REL);
        }
    }
    int s_m   = __shfl(s_ld, m, 64);
    int t_m   = __shfl(t_ld, m, 64);
    int eid_m = __shfl(e_ld, m, 64);
    int r_m   = __shfl(r_ld, m, 64);
    int r0    = __shfl(r_ld, 0, 64);
    bool sorted = (perm4 != nullptr) || (permi != nullptr);

    // ---- gather A-operand data (lane holds edge m, k = 8q..8q+7) ----
    const float* sp = node_feat + s_m * DIM + q * 8;
    float4 sv0 = *(const float4*)sp, sv1 = *(const float4*)(sp + 4);
    const float* tp = node_feat + t_m * DIM + q * 8;
    float4 tv0 = *(const float4*)tp, tv1 = *(const float4*)(tp + 4);
    const float* rp = tre + eid_m * DIM + q * 8;
    float4 rv0 = *(const float4*)rp, rv1 = *(const float4*)(rp + 4);
    const float* qp = ttr + eid_m * DIM + q * 8;
    float4 qv0 = *(const float4*)qp, qv1 = *(const float4*)(qp + 4);

    short8 fsrc = cvt8(sv0, sv1);
    short8 ftgt = cvt8(tv0, tv1);
    short8 fre  = cvt8(rv0, rv1);
    short8 ftr  = cvt8(qv0, qv1);

    // ---- B-operand fragments (lane: n = m, k = 8q..8q+7) ----
    short8 bA[4][2], bS[2];
    #pragma unroll
    for (int hh = 0; hh < 2; hh++) {
        #pragma unroll
        for (int c = 0; c < 4; c++)
            bA[c][hh] = *(const short8*)(aw_bf + (16 * hh + m) * 128 + 32 * c + 8 * q);
        bS[hh] = *(const short8*)(slwT_bf + (16 * hh + m) * 32 + 8 * q);
    }

    // ---- MFMAs: h = Ecat @ Aw^T + Ab ; cur = tgt @ slw ----
    float ab0 = Ab[m], ab1 = Ab[16 + m];
    f32x4 hacc0 = {ab0, ab0, ab0, ab0};
    f32x4 hacc1 = {ab1, ab1, ab1, ab1};
    f32x4 cacc0 = {0.f, 0.f, 0.f, 0.f};
    f32x4 cacc1 = {0.f, 0.f, 0.f, 0.f};

    hacc0 = MFMA(fsrc, bA[0][0], hacc0);  hacc1 = MFMA(fsrc, bA[0][1], hacc1);
    hacc0 = MFMA(ftgt, bA[1][0], hacc0);  hacc1 = MFMA(ftgt, bA[1][1], hacc1);
    hacc0 = MFMA(fre,  bA[2][0], hacc0);  hacc1 = MFMA(fre,  bA[2][1], hacc1);
    hacc0 = MFMA(ftr,  bA[3][0], hacc0);  hacc1 = MFMA(ftr,  bA[3][1], hacc1);
    cacc0 = MFMA(ftgt, bS[0], cacc0);     cacc1 = MFMA(ftgt, bS[1], cacc1);

    // ---- msg: MFMA when wave is relation-uniform (sorted), else VALU ----
    f32x4 macc0 = {0.f, 0.f, 0.f, 0.f};
    f32x4 macc1 = {0.f, 0.f, 0.f, 0.f};
    bool uni = sorted && __all(r_m == r0);
    if (uni) {
        // relw_bf is transposed: B[k][n] at relw[n*32+k]
        const unsigned short* rwt = relw_bf + r0 * 1024;
        short8 bM0 = *(const short8*)(rwt + m * 32 + 8 * q);
        short8 bM1 = *(const short8*)(rwt + (16 + m) * 32 + 8 * q);
        macc0 = MFMA(fsrc, bM0, macc0);
        macc1 = MFMA(fsrc, bM1, macc1);
    } else {
        // scalar fallback: lane = (edge e_loc, col-chunk cq*8..+7)
        int e_loc = lane >> 2;
        int cq    = lane & 3;
        int r_e = __shfl(r_ld, e_loc, 64);
        float sf[8] = {sv0.x, sv0.y, sv0.z, sv0.w, sv1.x, sv1.y, sv1.z, sv1.w};
        float msg[8] = {0.f, 0.f, 0.f, 0.f, 0.f, 0.f, 0.f, 0.f};
        const unsigned short* rw = relw_bf + r_e * 1024;
        #pragma unroll 4
        for (int k = 0; k < 32; k++) {
            float s_k = __shfl(sf[k & 7], e_loc + 16 * (k >> 3), 64);
            if (sorted) {
                // transposed layout: rel_w[k][n] at rw[n*32+k]
                #pragma unroll
                for (int p = 0; p < 8; p++)
                    msg[p] = fmaf(s_k, bf2f(rw[(cq * 8 + p) * 32 + k]), msg[p]);
            } else {
                // row-major: rel_w[k][n] at rw[k*32+n]
                union { short8 s; unsigned u[4]; } W;
                W.s = *(const short8*)(rw + k * 32 + cq * 8);
                #pragma unroll
                for (int p = 0; p < 4; p++) {
                    msg[2 * p]     = fmaf(s_k, __uint_as_float(W.u[p] << 16), msg[2 * p]);
                    msg[2 * p + 1] = fmaf(s_k, __uint_as_float(W.u[p] & 0xffff0000u), msg[2 * p + 1]);
                }
            }
        }
        // relayout into C/D via this wave's private LDS slice
        float* ml = msgL + wave * (16 * 36);
        *(float4*)(ml + e_loc * 36 + cq * 8)     = make_float4(msg[0], msg[1], msg[2], msg[3]);
        *(float4*)(ml + e_loc * 36 + cq * 8 + 4) = make_float4(msg[4], msg[5], msg[6], msg[7]);
        #pragma unroll
        for (int v = 0; v < 4; v++) {
            macc0[v] = ml[(4 * q + v) * 36 + m];
            macc1[v] = ml[(4 * q + v) * 36 + 16 + m];
        }
    }

    // ---- epilogue: gate a = sigmoid(relu(h)@Bw + Bb), combine, scatter ----
    float bw0 = Bw[m], bw1 = Bw[16 + m], Bb0 = Bb[0];
    float av[4];
    #pragma unroll
    for (int v = 0; v < 4; v++) {
        float p = fmaxf(hacc0[v], 0.f) * bw0 + fmaxf(hacc1[v], 0.f) * bw1;
        p += __shfl_xor(p, 1, 16);
        p += __shfl_xor(p, 2, 16);
        p += __shfl_xor(p, 4, 16);
        p += __shfl_xor(p, 8, 16);
        av[v] = 1.f / (1.f + __expf(-(p + Bb0)));
    }
    #pragma unroll
    for (int v = 0; v < 4; v++) {
        int row = 4 * q + v;
        int tv = __shfl(t_ld, row, 64);
        atomicAdd(&out[tv * DIM + m],      cacc0[v] + macc0[v] * av[v]);
        atomicAdd(&out[tv * DIM + 16 + m], cacc1[v] + macc1[v] * av[v]);
    }
}

extern "C" void kernel_launch(void* const* d_in, const int* in_sizes, int n_in,
                              void* d_out, int out_size, void* d_ws, size_t ws_size,
                              hipStream_t stream) {
    const float* node_feat = (const float*)d_in[0];
    const float* ttr       = (const float*)d_in[1];
    const float* tre       = (const float*)d_in[2];
    const float* weight    = (const float*)d_in[3];
    const float* w_comp    = (const float*)d_in[4];
    const float* slw       = (const float*)d_in[5];
    const float* Aw        = (const float*)d_in[6];
    const float* Ab        = (const float*)d_in[7];
    const float* Bw        = (const float*)d_in[8];
    const float* Bb        = (const float*)d_in[9];
    const int*  total_edge = (const int*)d_in[10];
    const int*  rel        = (const int*)d_in[11];
    const int*  edge0 = total_edge;
    const int*  edge1 = total_edge + N_EDGES;

    unsigned short* relw_bf = (unsigned short*)d_ws;
    unsigned short* aw_bf   = (unsigned short*)((char*)d_ws + AWBF_OFF);
    unsigned short* slwT_bf = (unsigned short*)((char*)d_ws + SLWT_OFF);
    int* bins = (int*)((char*)d_ws + BINS_OFF);
    int* gcur = (int*)((char*)d_ws + GCUR_OFF);
    float* out = (float*)d_out;

    int tierA = ws_size >= (size_t)WS_A;
    int tierB = !tierA && ws_size >= (size_t)WS_B;
    int sorted = tierA || tierB;
    int4* perm4 = tierA ? (int4*)((char*)d_ws + PERM_OFF) : nullptr;
    int*  permi = tierB ? (int*)((char*)d_ws + PERM_OFF) : nullptr;

    if (sorted) hipMemsetAsync(bins, 0, 1600, stream);   // bins + gcur

    int prep_blocks = N_REL + ZERO_BLOCKS + 1 + (sorted ? HIST_BLOCKS : 0);
    prep_kernel<<<prep_blocks, 256, 0, stream>>>(
        weight, w_comp, Aw, slw, rel, relw_bf, aw_bf, slwT_bf, bins, out, sorted);

    if (sorted)
        scatter_kernel<<<HIST_BLOCKS, 256, 0, stream>>>(
            rel, edge0, edge1, bins, gcur, perm4, permi);

    edge_kernel<<<N_EDGES / 64, 256, 0, stream>>>(
        node_feat, ttr, tre, Ab, Bw, Bb,
        edge0, edge1, rel, perm4, permi,
        relw_bf, aw_bf, slwT_bf, out);
}

// Round 8
// 153.226 us; speedup vs baseline: 1.0830x; 1.0407x over previous
//
#include <hip/hip_runtime.h>

// Problem constants (from reference)
#define N_NODES 12500
#define N_EDGES 200000
#define DIM 32          // IN == OUT == ATTN == 32
#define N_REL 200
#define N_BASES 50

#define OUT_ELEMS   (N_NODES * DIM)
#define ZERO_BLOCKS ((OUT_ELEMS + 1023) / 1024)   // 391

#define EDGES_PER_HBLOCK 1024
#define HIST_BLOCKS ((N_EDGES + EDGES_PER_HBLOCK - 1) / EDGES_PER_HBLOCK)  // 196

// ws layout (bytes):
//   [0, 409600)       bf16 relw_bf[200][32][32]  (TRANSPOSED [o][i] when sorted,
//                                                 row-major [i][o] when unsorted)
//   [409600, +8192)   bf16 aw_bf[32][128]
//   [417792, +2048)   bf16 slwT_bf[32][32]   (transposed [j][i])
//   [419840, +800)    int  bins[200]
//   [420640, +800)    int  gcur[200]
//   [421440, ...)     perm: int4[200000] (tier A) or int[200000] (tier B)
#define AWBF_OFF  409600
#define SLWT_OFF  417792
#define BINS_OFF  419840
#define GCUR_OFF  420640
#define PERM_OFF  421440
#define WS_A (PERM_OFF + N_EDGES * 16)   // 3,621,440
#define WS_B (PERM_OFF + N_EDGES * 4)    // 1,221,440

typedef __attribute__((ext_vector_type(8))) short short8;   // 8 bf16 (4 VGPRs)
typedef __attribute__((ext_vector_type(4))) float f32x4;    // MFMA acc
typedef __attribute__((ext_vector_type(4))) unsigned short us4;

__device__ __forceinline__ unsigned short f2bf(float x) {
    union { float f; unsigned u; } v; v.f = x;
    unsigned r = (v.u + 0x7FFFu + ((v.u >> 16) & 1u)) >> 16;
    return (unsigned short)r;
}
__device__ __forceinline__ float bf2f(unsigned short u) {
    return __uint_as_float(((unsigned)u) << 16);
}

__device__ __forceinline__ short8 cvt8(float4 a, float4 b) {
    short8 r;
    r[0] = (short)f2bf(a.x); r[1] = (short)f2bf(a.y);
    r[2] = (short)f2bf(a.z); r[3] = (short)f2bf(a.w);
    r[4] = (short)f2bf(b.x); r[5] = (short)f2bf(b.y);
    r[6] = (short)f2bf(b.z); r[7] = (short)f2bf(b.w);
    return r;
}

__device__ __forceinline__ int clampi(int x, int hi) {
    return x < 0 ? 0 : (x >= hi ? hi - 1 : x);
}

#define MFMA(A, B, C) __builtin_amdgcn_mfma_f32_16x16x32_bf16(A, B, C, 0, 0, 0)

// K1 prep (fused): [0,200) rel_w; [200,591) zero out; 591 cvt Aw/slwT;
// [592, 592+196) relation histogram (bins pre-zeroed by memsetAsync).
__global__ __launch_bounds__(256) void prep_kernel(
    const float* __restrict__ weight,   // [50,32,32]
    const float* __restrict__ w_comp,   // [200,50]
    const float* __restrict__ Aw,       // [32,128]
    const float* __restrict__ slw,      // [32,32]
    const int*  __restrict__ rel,       // [E]
    unsigned short* __restrict__ relw_bf,
    unsigned short* __restrict__ aw_bf,
    unsigned short* __restrict__ slwT_bf,
    int* __restrict__ bins,
    float* __restrict__ out,
    int sorted)
{
    int b = blockIdx.x, tid = threadIdx.x;
    if (b < N_REL) {
        __shared__ float wc[N_BASES];
        if (tid < N_BASES) wc[tid] = w_comp[b * N_BASES + tid];
        __syncthreads();
        const float* wp = weight + tid * 4;
        float4 acc = make_float4(0.f, 0.f, 0.f, 0.f);
        #pragma unroll 10
        for (int bb = 0; bb < N_BASES; bb++) {
            float4 w = *(const float4*)(wp + bb * 1024);
            float c = wc[bb];
            acc.x = fmaf(c, w.x, acc.x); acc.y = fmaf(c, w.y, acc.y);
            acc.z = fmaf(c, w.z, acc.z); acc.w = fmaf(c, w.w, acc.w);
        }
        int i = (tid * 4) >> 5, o = (tid * 4) & 31;   // rel_w[i][o..o+3]
        if (sorted) {
            // transposed (B-frag) layout: relw[o+j][i]
            relw_bf[b * 1024 + (o + 0) * 32 + i] = f2bf(acc.x);
            relw_bf[b * 1024 + (o + 1) * 32 + i] = f2bf(acc.y);
            relw_bf[b * 1024 + (o + 2) * 32 + i] = f2bf(acc.z);
            relw_bf[b * 1024 + (o + 3) * 32 + i] = f2bf(acc.w);
        } else {
            us4 ov;
            ov[0] = f2bf(acc.x); ov[1] = f2bf(acc.y);
            ov[2] = f2bf(acc.z); ov[3] = f2bf(acc.w);
            *(us4*)(relw_bf + b * 1024 + tid * 4) = ov;
        }
    } else if (b < N_REL + ZERO_BLOCKS) {
        int base = (b - N_REL) * 1024 + tid * 4;
        if (base + 3 < OUT_ELEMS)
            *(float4*)(out + base) = make_float4(0.f, 0.f, 0.f, 0.f);
        else
            for (int k = 0; k < 4; k++)
                if (base + k < OUT_ELEMS) out[base + k] = 0.f;
    } else if (b == N_REL + ZERO_BLOCKS) {
        for (int x = tid; x < 32 * 128; x += 256) aw_bf[x] = f2bf(Aw[x]);
        for (int x = tid; x < 32 * 32; x += 256) {
            int i = x >> 5, j = x & 31;
            slwT_bf[j * 32 + i] = f2bf(slw[x]);
        }
    } else {
        // histogram block
        __shared__ int lb[N_REL];
        if (tid < N_REL) lb[tid] = 0;
        __syncthreads();
        int base = (b - (N_REL + ZERO_BLOCKS + 1)) * EDGES_PER_HBLOCK + tid;
        #pragma unroll
        for (int k = 0; k < 4; k++) {
            int e = base + k * 256;
            if (e < N_EDGES) atomicAdd(&lb[clampi(rel[e], N_REL)], 1);
        }
        __syncthreads();
        if (tid < N_REL && lb[tid] > 0) atomicAdd(&bins[tid], lb[tid]);
    }
}

// K2 scatter: local prefix-from-bins + global rank via gcur.
// Tier A writes int4{s,t,r,eid}; tier B writes int eid.
__global__ __launch_bounds__(256) void scatter_kernel(
    const int* __restrict__ rel,
    const int* __restrict__ edge0,
    const int* __restrict__ edge1,
    const int* __restrict__ bins,
    int* __restrict__ gcur,
    int4* __restrict__ perm4,    // tier A (or null)
    int* __restrict__ permi)     // tier B (or null)
{
    __shared__ int sb[N_REL];
    __shared__ int pref[N_REL];
    __shared__ int lb[N_REL];
    int tid = threadIdx.x;
    if (tid < N_REL) { sb[tid] = bins[tid]; lb[tid] = 0; }
    __syncthreads();
    if (tid == 0) {
        int run = 0;
        for (int r = 0; r < N_REL; r++) { pref[r] = run; run += sb[r]; }
    }
    __syncthreads();
    int base = blockIdx.x * EDGES_PER_HBLOCK + tid;
    int myr[4], myrank[4];
    #pragma unroll
    for (int k = 0; k < 4; k++) {
        int e = base + k * 256;
        myr[k] = -1;
        if (e < N_EDGES) {
            myr[k] = clampi(rel[e], N_REL);
            myrank[k] = atomicAdd(&lb[myr[k]], 1);
        }
    }
    __syncthreads();
    if (tid < N_REL) {
        int c = lb[tid];
        lb[tid] = c > 0 ? (pref[tid] + atomicAdd(&gcur[tid], c)) : 0;
    }
    __syncthreads();
    #pragma unroll
    for (int k = 0; k < 4; k++) {
        if (myr[k] >= 0) {
            int e = base + k * 256;
            int pos = lb[myr[k]] + myrank[k];
            if (perm4) {
                int s = clampi(edge0[e], N_NODES);
                int t = clampi(edge1[e], N_NODES);
                perm4[pos] = make_int4(s, t, myr[k], e);
            } else {
                permi[pos] = e;
            }
        }
    }
}

// K3 edge kernel: one wave = 64 relation-sorted edges (4 sub-batches of 16).
// perm4 read is one coalesced 1KB wave-load; aw/slwT B-frags loaded once per
// wave; relw frags hoisted when the whole wave is relation-uniform (~93% of
// waves). h/cur/msg all MFMA; rare mixed sub-batches take a VALU fallback.
__global__ __launch_bounds__(256) void edge_kernel(
    const float* __restrict__ node_feat,  // [N,32]
    const float* __restrict__ ttr,        // [E,32]
    const float* __restrict__ tre,        // [E,32]
    const float* __restrict__ Ab,         // [32]
    const float* __restrict__ Bw,         // [1,32]
    const float* __restrict__ Bb,         // [1]
    const int*  __restrict__ edge0,       // [E]
    const int*  __restrict__ edge1,       // [E]
    const int*  __restrict__ rel,         // [E]
    const int4* __restrict__ perm4,       // tier A packed (or null)
    const int*  __restrict__ permi,       // tier B (or null)
    const unsigned short* __restrict__ relw_bf, // [200][32][32] bf16 (T if sorted)
    const unsigned short* __restrict__ aw_bf,   // [32][128] bf16
    const unsigned short* __restrict__ slwT_bf, // [32][32]  bf16 (T)
    float* __restrict__ out)              // [N,32] fp32 (pre-zeroed)
{
    __shared__ float msgL[4 * 16 * 36];   // fallback relayout slices (9.2 KB)

    int tid  = threadIdx.x;
    int wave = tid >> 6;
    int lane = tid & 63;
    int m = lane & 15;          // edge row (A-frag) / out col n (B,C/D frag)
    int q = lane >> 4;          // quad: k-range / row-group
    int base = blockIdx.x * 256 + wave * 64;
    if (base >= N_EDGES) return;

    bool sorted = (perm4 != nullptr) || (permi != nullptr);

    // all 64 lanes hold one edge's indices (coalesced 1KB perm4 load)
    int s_l, t_l, r_l, e_l;
    if (perm4) {
        int4 pv = perm4[base + lane];
        s_l = pv.x; t_l = pv.y; r_l = pv.z; e_l = pv.w;
    } else {
        int eid = permi ? clampi(permi[base + lane], N_EDGES) : (base + lane);
        e_l = eid;
        s_l = clampi(edge0[eid], N_NODES);
        t_l = clampi(edge1[eid], N_NODES);
        r_l = clampi(rel[eid],   N_REL);
    }

    // ---- B-operand fragments, loaded ONCE per wave ----
    short8 bA[4][2], bS[2];
    #pragma unroll
    for (int hh = 0; hh < 2; hh++) {
        #pragma unroll
        for (int c = 0; c < 4; c++)
            bA[c][hh] = *(const short8*)(aw_bf + (16 * hh + m) * 128 + 32 * c + 8 * q);
        bS[hh] = *(const short8*)(slwT_bf + (16 * hh + m) * 32 + 8 * q);
    }
    float ab0 = Ab[m], ab1 = Ab[16 + m];
    float bw0 = Bw[m], bw1 = Bw[16 + m], Bb0 = Bb[0];

    // wave-level relation uniformity: hoist msg B-frags (~93% of waves)
    int r0 = __shfl(r_l, 0, 64);
    bool uniWave = sorted && __all(r_l == r0);
    short8 bM0w = {}, bM1w = {};
    if (uniWave) {
        const unsigned short* rwt = relw_bf + r0 * 1024;
        bM0w = *(const short8*)(rwt + m * 32 + 8 * q);
        bM1w = *(const short8*)(rwt + (16 + m) * 32 + 8 * q);
    }

    #pragma unroll
    for (int sb = 0; sb < 4; sb++) {
        int lb = sb * 16;
        int s_m   = __shfl(s_l, lb + m, 64);
        int t_m   = __shfl(t_l, lb + m, 64);
        int eid_m = __shfl(e_l, lb + m, 64);

        // gather A-operand data (lane holds edge m of this sub-batch, k=8q..8q+7)
        const float* sp = node_feat + s_m * DIM + q * 8;
        float4 sv0 = *(const float4*)sp, sv1 = *(const float4*)(sp + 4);
        const float* tp = node_feat + t_m * DIM + q * 8;
        float4 tv0 = *(const float4*)tp, tv1 = *(const float4*)(tp + 4);
        const float* rp = tre + eid_m * DIM + q * 8;
        float4 rv0 = *(const float4*)rp, rv1 = *(const float4*)(rp + 4);
        const float* qp = ttr + eid_m * DIM + q * 8;
        float4 qv0 = *(const float4*)qp, qv1 = *(const float4*)(qp + 4);

        short8 fsrc = cvt8(sv0, sv1);
        short8 ftgt = cvt8(tv0, tv1);
        short8 fre  = cvt8(rv0, rv1);
        short8 ftr  = cvt8(qv0, qv1);

        f32x4 hacc0 = {ab0, ab0, ab0, ab0};
        f32x4 hacc1 = {ab1, ab1, ab1, ab1};
        f32x4 cacc0 = {0.f, 0.f, 0.f, 0.f};
        f32x4 cacc1 = {0.f, 0.f, 0.f, 0.f};

        hacc0 = MFMA(fsrc, bA[0][0], hacc0);  hacc1 = MFMA(fsrc, bA[0][1], hacc1);
        hacc0 = MFMA(ftgt, bA[1][0], hacc0);  hacc1 = MFMA(ftgt, bA[1][1], hacc1);
        hacc0 = MFMA(fre,  bA[2][0], hacc0);  hacc1 = MFMA(fre,  bA[2][1], hacc1);
        hacc0 = MFMA(ftr,  bA[3][0], hacc0);  hacc1 = MFMA(ftr,  bA[3][1], hacc1);
        cacc0 = MFMA(ftgt, bS[0], cacc0);     cacc1 = MFMA(ftgt, bS[1], cacc1);

        // msg
        f32x4 macc0 = {0.f, 0.f, 0.f, 0.f};
        f32x4 macc1 = {0.f, 0.f, 0.f, 0.f};
        int r_sb = __shfl(r_l, lb + m, 64);
        int r00  = __shfl(r_l, lb, 64);
        bool uni = uniWave || (sorted && __all(r_sb == r00));
        if (uni) {
            short8 bM0 = bM0w, bM1 = bM1w;
            if (!uniWave) {
                const unsigned short* rwt = relw_bf + r00 * 1024;
                bM0 = *(const short8*)(rwt + m * 32 + 8 * q);
                bM1 = *(const short8*)(rwt + (16 + m) * 32 + 8 * q);
            }
            macc0 = MFMA(fsrc, bM0, macc0);
            macc1 = MFMA(fsrc, bM1, macc1);
        } else {
            // scalar fallback: lane = (edge e_loc, col-chunk cq*8..+7)
            int e_loc = lane >> 2;
            int cq    = lane & 3;
            int r_e = __shfl(r_l, lb + e_loc, 64);
            float sf[8] = {sv0.x, sv0.y, sv0.z, sv0.w, sv1.x, sv1.y, sv1.z, sv1.w};
            float msg[8] = {0.f, 0.f, 0.f, 0.f, 0.f, 0.f, 0.f, 0.f};
            const unsigned short* rw = relw_bf + r_e * 1024;
            #pragma unroll 4
            for (int k = 0; k < 32; k++) {
                float s_k = __shfl(sf[k & 7], e_loc + 16 * (k >> 3), 64);
                if (sorted) {
                    // transposed layout: rel_w[k][n] at rw[n*32+k]
                    #pragma unroll
                    for (int p = 0; p < 8; p++)
                        msg[p] = fmaf(s_k, bf2f(rw[(cq * 8 + p) * 32 + k]), msg[p]);
                } else {
                    union { short8 s; unsigned u[4]; } W;
                    W.s = *(const short8*)(rw + k * 32 + cq * 8);
                    #pragma unroll
                    for (int p = 0; p < 4; p++) {
                        msg[2 * p]     = fmaf(s_k, __uint_as_float(W.u[p] << 16), msg[2 * p]);
                        msg[2 * p + 1] = fmaf(s_k, __uint_as_float(W.u[p] & 0xffff0000u), msg[2 * p + 1]);
                    }
                }
            }
            float* ml = msgL + wave * (16 * 36);
            *(float4*)(ml + e_loc * 36 + cq * 8)     = make_float4(msg[0], msg[1], msg[2], msg[3]);
            *(float4*)(ml + e_loc * 36 + cq * 8 + 4) = make_float4(msg[4], msg[5], msg[6], msg[7]);
            #pragma unroll
            for (int v = 0; v < 4; v++) {
                macc0[v] = ml[(4 * q + v) * 36 + m];
                macc1[v] = ml[(4 * q + v) * 36 + 16 + m];
            }
        }

        // epilogue: gate + combine + scatter-add
        float av[4];
        #pragma unroll
        for (int v = 0; v < 4; v++) {
            float p = fmaxf(hacc0[v], 0.f) * bw0 + fmaxf(hacc1[v], 0.f) * bw1;
            p += __shfl_xor(p, 1, 16);
            p += __shfl_xor(p, 2, 16);
            p += __shfl_xor(p, 4, 16);
            p += __shfl_xor(p, 8, 16);
            av[v] = 1.f / (1.f + __expf(-(p + Bb0)));
        }
        #pragma unroll
        for (int v = 0; v < 4; v++) {
            int row = 4 * q + v;
            int tv = __shfl(t_l, lb + row, 64);
            atomicAdd(&out[tv * DIM + m],      cacc0[v] + macc0[v] * av[v]);
            atomicAdd(&out[tv * DIM + 16 + m], cacc1[v] + macc1[v] * av[v]);
        }
    }
}

extern "C" void kernel_launch(void* const* d_in, const int* in_sizes, int n_in,
                              void* d_out, int out_size, void* d_ws, size_t ws_size,
                              hipStream_t stream) {
    const float* node_feat = (const float*)d_in[0];
    const float* ttr       = (const float*)d_in[1];
    const float* tre       = (const float*)d_in[2];
    const float* weight    = (const float*)d_in[3];
    const float* w_comp    = (const float*)d_in[4];
    const float* slw       = (const float*)d_in[5];
    const float* Aw        = (const float*)d_in[6];
    const float* Ab        = (const float*)d_in[7];
    const float* Bw        = (const float*)d_in[8];
    const float* Bb        = (const float*)d_in[9];
    const int*  total_edge = (const int*)d_in[10];
    const int*  rel        = (const int*)d_in[11];
    const int*  edge0 = total_edge;
    const int*  edge1 = total_edge + N_EDGES;

    unsigned short* relw_bf = (unsigned short*)d_ws;
    unsigned short* aw_bf   = (unsigned short*)((char*)d_ws + AWBF_OFF);
    unsigned short* slwT_bf = (unsigned short*)((char*)d_ws + SLWT_OFF);
    int* bins = (int*)((char*)d_ws + BINS_OFF);
    int* gcur = (int*)((char*)d_ws + GCUR_OFF);
    float* out = (float*)d_out;

    int tierA = ws_size >= (size_t)WS_A;
    int tierB = !tierA && ws_size >= (size_t)WS_B;
    int sorted = tierA || tierB;
    int4* perm4 = tierA ? (int4*)((char*)d_ws + PERM_OFF) : nullptr;
    int*  permi = tierB ? (int*)((char*)d_ws + PERM_OFF) : nullptr;

    if (sorted) hipMemsetAsync(bins, 0, 1600, stream);   // bins + gcur

    int prep_blocks = N_REL + ZERO_BLOCKS + 1 + (sorted ? HIST_BLOCKS : 0);
    prep_kernel<<<prep_blocks, 256, 0, stream>>>(
        weight, w_comp, Aw, slw, rel, relw_bf, aw_bf, slwT_bf, bins, out, sorted);

    if (sorted)
        scatter_kernel<<<HIST_BLOCKS, 256, 0, stream>>>(
            rel, edge0, edge1, bins, gcur, perm4, permi);

    edge_kernel<<<(N_EDGES + 255) / 256, 256, 0, stream>>>(
        node_feat, ttr, tre, Ab, Bw, Bb,
        edge0, edge1, rel, perm4, permi,
        relw_bf, aw_bf, slwT_bf, out);
}